// Round 1
// baseline (340.365 us; speedup 1.0000x reference)
//
#include <hip/hip_runtime.h>
#include <hip/hip_bf16.h>

// MessagePassing: out[dst[e], :] += x[src[e], :] * w[e]
// x: [N, 64] f32, edge_index: [2, E] int32 (row0=src, row1=dst), w: [E,1] f32
// out: [N, 64] f32

constexpr int N_NODES = 100000;
constexpr int N_EDGES = 1200000;
constexpr int D_FEAT  = 64;

// One wave (64 lanes) per edge; lane index == feature index.
__global__ __launch_bounds__(256) void mp_scatter_kernel(
    const float* __restrict__ x,
    const int*   __restrict__ src,
    const int*   __restrict__ dst,
    const float* __restrict__ w,
    float*       __restrict__ out,
    int n_edges)
{
    const int gtid = blockIdx.x * blockDim.x + threadIdx.x;
    const int edge = gtid >> 6;          // wave id = edge id
    const int lane = threadIdx.x & 63;   // feature id
    if (edge >= n_edges) return;

    // Wave-uniform loads (compiler emits scalar load + broadcast)
    const int   s  = src[edge];
    const int   d  = dst[edge];
    const float ww = w[edge];

    const float v = x[(long)s * D_FEAT + lane] * ww;
    atomicAdd(&out[(long)d * D_FEAT + lane], v);
}

extern "C" void kernel_launch(void* const* d_in, const int* in_sizes, int n_in,
                              void* d_out, int out_size, void* d_ws, size_t ws_size,
                              hipStream_t stream)
{
    const float* x          = (const float*)d_in[0];
    const int*   edge_index = (const int*)d_in[1];   // [2, E]
    const float* w          = (const float*)d_in[2]; // [E, 1]
    float*       out        = (float*)d_out;

    const int n_edges = in_sizes[1] / 2;
    const int*   src = edge_index;
    const int*   dst = edge_index + n_edges;

    // Harness poisons d_out with 0xAA before every timed launch — zero it.
    hipMemsetAsync(d_out, 0, (size_t)out_size * sizeof(float), stream);

    // One wave per edge: 4 edges per 256-thread block.
    const int edges_per_block = 256 / 64;
    const int grid = (n_edges + edges_per_block - 1) / edges_per_block;
    mp_scatter_kernel<<<grid, 256, 0, stream>>>(x, src, dst, w, out, n_edges);
}

// Round 2
// 287.747 us; speedup vs baseline: 1.1829x; 1.1829x over previous
//
#include <hip/hip_runtime.h>
#include <hip/hip_bf16.h>

// MessagePassing: out[dst[e], :] += x[src[e], :] * w[e]
// x: [N, 64] f32, edge_index: [2, E] int32 (row0=src, row1=dst), w: [E,1] f32
// out: [N, 64] f32
//
// Strategy: per-call CSR bucketing by dst (hist -> scan -> scatter) then an
// atomic-free gather: one wave per node, register accumulate, single row store.

constexpr int D_FEAT = 64;

// ---------------- fallback path (round-1): atomic scatter ----------------
__global__ __launch_bounds__(256) void mp_scatter_atomic(
    const float* __restrict__ x, const int* __restrict__ src,
    const int* __restrict__ dst, const float* __restrict__ w,
    float* __restrict__ out, int n_edges)
{
    const int gtid = blockIdx.x * blockDim.x + threadIdx.x;
    const int edge = gtid >> 6;
    const int lane = threadIdx.x & 63;
    if (edge >= n_edges) return;
    const int s = src[edge];
    const int d = dst[edge];
    const float ww = w[edge];
    const float v = x[(size_t)s * D_FEAT + lane] * ww;
    atomicAdd(&out[(size_t)d * D_FEAT + lane], v);
}

// ---------------- CSR build ----------------
__global__ __launch_bounds__(256) void mp_hist(
    const int* __restrict__ dst, int* __restrict__ deg, int n_edges)
{
    const int i = blockIdx.x * blockDim.x + threadIdx.x;
    if (i < n_edges) atomicAdd(&deg[dst[i]], 1);
}

__device__ __forceinline__ int wave_incl_scan(int v, int lane) {
    #pragma unroll
    for (int d = 1; d < 64; d <<= 1) {
        int t = __shfl_up(v, d);
        if (lane >= d) v += t;
    }
    return v;
}

// Per-block (256 elems) sums
__global__ __launch_bounds__(256) void mp_scan_blocksums(
    const int* __restrict__ deg, int* __restrict__ bsums, int n)
{
    __shared__ int wsum[4];
    const int i = blockIdx.x * 256 + threadIdx.x;
    const int lane = threadIdx.x & 63;
    const int wid = threadIdx.x >> 6;
    int v = (i < n) ? deg[i] : 0;
    // wave reduce
    #pragma unroll
    for (int d = 32; d >= 1; d >>= 1) v += __shfl_down(v, d);
    if (lane == 0) wsum[wid] = v;
    __syncthreads();
    if (threadIdx.x == 0)
        bsums[blockIdx.x] = wsum[0] + wsum[1] + wsum[2] + wsum[3];
}

// Single-block Hillis-Steele scan of block sums (nb <= 1024) -> exclusive
__global__ __launch_bounds__(1024) void mp_scan_bsums(int* __restrict__ bsums, int nb)
{
    __shared__ int sh[1024];
    const int t = threadIdx.x;
    int v = (t < nb) ? bsums[t] : 0;
    sh[t] = v;
    __syncthreads();
    #pragma unroll
    for (int d = 1; d < 1024; d <<= 1) {
        int addv = (t >= d) ? sh[t - d] : 0;
        __syncthreads();
        sh[t] += addv;
        __syncthreads();
    }
    if (t < nb) bsums[t] = sh[t] - v;  // exclusive
}

// Final: offsets[i] = exclusive prefix; also copy to cursor (in-place over deg)
__global__ __launch_bounds__(256) void mp_scan_final(
    int* __restrict__ deg_off, int* __restrict__ cursor,
    const int* __restrict__ bsums, int n)
{
    __shared__ int wsum[4];
    const int i = blockIdx.x * 256 + threadIdx.x;
    const int lane = threadIdx.x & 63;
    const int wid = threadIdx.x >> 6;
    int v = (i < n) ? deg_off[i] : 0;
    int incl = wave_incl_scan(v, lane);
    if (lane == 63) wsum[wid] = incl;
    __syncthreads();
    int woff = 0;
    #pragma unroll
    for (int k = 0; k < 4; ++k) woff += (k < wid) ? wsum[k] : 0;
    const int excl = incl - v + woff + bsums[blockIdx.x];
    if (i < n) {
        deg_off[i] = excl;
        cursor[i]  = excl;
    }
}

// Scatter edges into dst-bucketed payload: (src, weight-bits)
__global__ __launch_bounds__(256) void mp_bucket(
    const int* __restrict__ src, const int* __restrict__ dst,
    const float* __restrict__ w, int* __restrict__ cursor,
    int2* __restrict__ payload, int n_edges)
{
    const int i = blockIdx.x * blockDim.x + threadIdx.x;
    if (i >= n_edges) return;
    const int d = dst[i];
    const int pos = atomicAdd(&cursor[d], 1);
    payload[pos] = make_int2(src[i], __float_as_int(w[i]));
}

// Atomic-free gather: one wave per node, lane = feature
__global__ __launch_bounds__(256) void mp_gather(
    const float* __restrict__ x, const int* __restrict__ off,
    const int2* __restrict__ payload, float* __restrict__ out,
    int n_nodes, int n_edges)
{
    const int gtid = blockIdx.x * blockDim.x + threadIdx.x;
    const int node = gtid >> 6;
    const int lane = threadIdx.x & 63;
    if (node >= n_nodes) return;

    const int beg = off[node];
    const int end = (node + 1 < n_nodes) ? off[node + 1] : n_edges;

    float acc = 0.f;
    int e = beg;
    // 2x unroll: two independent gathers in flight
    for (; e + 1 < end; e += 2) {
        const int2 p0 = payload[e];
        const int2 p1 = payload[e + 1];
        const float x0 = x[(size_t)p0.x * D_FEAT + lane];
        const float x1 = x[(size_t)p1.x * D_FEAT + lane];
        acc = fmaf(x0, __int_as_float(p0.y), acc);
        acc = fmaf(x1, __int_as_float(p1.y), acc);
    }
    if (e < end) {
        const int2 p = payload[e];
        acc = fmaf(x[(size_t)p.x * D_FEAT + lane], __int_as_float(p.y), acc);
    }
    out[(size_t)node * D_FEAT + lane] = acc;
}

extern "C" void kernel_launch(void* const* d_in, const int* in_sizes, int n_in,
                              void* d_out, int out_size, void* d_ws, size_t ws_size,
                              hipStream_t stream)
{
    const float* x          = (const float*)d_in[0];
    const int*   edge_index = (const int*)d_in[1];   // [2, E]
    const float* w          = (const float*)d_in[2]; // [E, 1]
    float*       out        = (float*)d_out;

    const int n_edges = in_sizes[1] / 2;
    const int n_nodes = in_sizes[0] / D_FEAT;
    const int* src = edge_index;
    const int* dst = edge_index + n_edges;

    const int nb = (n_nodes + 255) / 256;   // scan blocks

    // Workspace layout (ints): [deg/offsets: nn_pad][cursor: nn_pad][bsums: 2048][payload: 2*E]
    const size_t nn_pad = ((size_t)n_nodes + 1023) & ~(size_t)1023;
    const size_t need_ints = 2 * nn_pad + 2048 + 2 * (size_t)n_edges;
    const size_t need_bytes = need_ints * 4;

    if (ws_size < need_bytes || nb > 1024) {
        // Fallback: round-1 atomic path
        hipMemsetAsync(d_out, 0, (size_t)out_size * sizeof(float), stream);
        const int grid = (n_edges * 64 + 255) / 256;
        mp_scatter_atomic<<<grid, 256, 0, stream>>>(x, src, dst, w, out, n_edges);
        return;
    }

    int*  deg_off = (int*)d_ws;
    int*  cursor  = deg_off + nn_pad;
    int*  bsums   = cursor + nn_pad;
    int2* payload = (int2*)(bsums + 2048);

    // 1. zero degree counts
    hipMemsetAsync(deg_off, 0, (size_t)n_nodes * 4, stream);
    // 2. histogram of dst
    mp_hist<<<(n_edges + 255) / 256, 256, 0, stream>>>(dst, deg_off, n_edges);
    // 3. scan (3 kernels)
    mp_scan_blocksums<<<nb, 256, 0, stream>>>(deg_off, bsums, n_nodes);
    mp_scan_bsums<<<1, 1024, 0, stream>>>(bsums, nb);
    mp_scan_final<<<nb, 256, 0, stream>>>(deg_off, cursor, bsums, n_nodes);
    // 4. bucket edges by dst
    mp_bucket<<<(n_edges + 255) / 256, 256, 0, stream>>>(src, dst, w, cursor, payload, n_edges);
    // 5. atomic-free gather, one wave per node
    const int gather_grid = ((n_nodes * 64) + 255) / 256;
    mp_gather<<<gather_grid, 256, 0, stream>>>(x, deg_off, payload, out, n_nodes, n_edges);
}

// Round 3
// 191.435 us; speedup vs baseline: 1.7780x; 1.5031x over previous
//
#include <hip/hip_runtime.h>
#include <hip/hip_bf16.h>

// MessagePassing: out[dst[e], :] += x[src[e], :] * w[e]
// x: [N, 64] f32, edge_index: [2, E] int32 (row0=src, row1=dst), w: [E,1] f32
// out: [N, 64] f32
//
// Round-3 strategy: fixed-capacity dst-buckets (no hist/scan). Bucket kernel
// scatters (src,w) into payload[dst*C + k] via per-node atomic counters;
// overflow edges (P ~ 3e-7/node at C=32) atomically add straight into the
// pre-zeroed out and raise a flag so gather read-accumulates. Gather: one
// wave per node, lane = feature, 4 independent edge streams.

constexpr int D_FEAT = 64;

// ---------------- final fallback: atomic scatter (round-1) ----------------
__global__ __launch_bounds__(256) void mp_scatter_atomic(
    const float* __restrict__ x, const int* __restrict__ src,
    const int* __restrict__ dst, const float* __restrict__ w,
    float* __restrict__ out, int n_edges)
{
    const int gtid = blockIdx.x * blockDim.x + threadIdx.x;
    const int edge = gtid >> 6;
    const int lane = threadIdx.x & 63;
    if (edge >= n_edges) return;
    const int s = src[edge];
    const int d = dst[edge];
    const float ww = w[edge];
    atomicAdd(&out[(size_t)d * D_FEAT + lane], x[(size_t)s * D_FEAT + lane] * ww);
}

// ---------------- capacity-bucket path ----------------
template <int C>
__global__ __launch_bounds__(256) void mp_bucket_cap(
    const int* __restrict__ src, const int* __restrict__ dst,
    const float* __restrict__ w, const float* __restrict__ x,
    int* __restrict__ cnt, int2* __restrict__ payload,
    int* __restrict__ ovf_flag, float* __restrict__ out, int n_edges)
{
    const int t  = blockIdx.x * blockDim.x + threadIdx.x;
    const int i0 = t * 4;
    if (i0 >= n_edges) return;

    int d[4], s[4];
    float ww[4];
    int nv;
    if (i0 + 4 <= n_edges) {
        nv = 4;
        const int4 dv = reinterpret_cast<const int4*>(dst)[t];
        const int4 sv = reinterpret_cast<const int4*>(src)[t];
        const float4 wv = reinterpret_cast<const float4*>(w)[t];
        d[0]=dv.x; d[1]=dv.y; d[2]=dv.z; d[3]=dv.w;
        s[0]=sv.x; s[1]=sv.y; s[2]=sv.z; s[3]=sv.w;
        ww[0]=wv.x; ww[1]=wv.y; ww[2]=wv.z; ww[3]=wv.w;
    } else {
        nv = n_edges - i0;
        #pragma unroll
        for (int k = 0; k < 4; ++k) {
            const int i = (k < nv) ? (i0 + k) : i0;
            d[k] = dst[i]; s[k] = src[i]; ww[k] = w[i];
        }
    }

    int pos[4];
    #pragma unroll
    for (int k = 0; k < 4; ++k)
        pos[k] = (k < nv) ? atomicAdd(&cnt[d[k]], 1) : C;  // 4 independent atomics

    #pragma unroll
    for (int k = 0; k < 4; ++k) {
        if (k >= nv) continue;
        if (pos[k] < C) {
            payload[(size_t)d[k] * C + pos[k]] = make_int2(s[k], __float_as_int(ww[k]));
        } else {
            // rare overflow: direct atomic accumulation into zeroed out
            atomicOr(ovf_flag, 1);
            const float* xr = x + (size_t)s[k] * D_FEAT;
            float* orow = out + (size_t)d[k] * D_FEAT;
            #pragma unroll 8
            for (int f = 0; f < D_FEAT; ++f)
                atomicAdd(&orow[f], xr[f] * ww[k]);
        }
    }
}

template <int C>
__global__ __launch_bounds__(256) void mp_gather_cap(
    const float* __restrict__ x, const int* __restrict__ cnt,
    const int2* __restrict__ payload, const int* __restrict__ ovf_flag,
    float* __restrict__ out, int n_nodes)
{
    const int gtid = blockIdx.x * blockDim.x + threadIdx.x;
    int node = gtid >> 6;
    const int lane = threadIdx.x & 63;
    if (node >= n_nodes) return;
    node = __builtin_amdgcn_readfirstlane(node);  // force SGPR -> scalar payload addressing

    const int m = min(cnt[node], C);
    const int2* pl = payload + (size_t)node * C;

    float a0 = 0.f, a1 = 0.f, a2 = 0.f, a3 = 0.f;
    int e = 0;
    for (; e + 4 <= m; e += 4) {
        const int2 p0 = pl[e + 0];
        const int2 p1 = pl[e + 1];
        const int2 p2 = pl[e + 2];
        const int2 p3 = pl[e + 3];
        const float v0 = x[(size_t)p0.x * D_FEAT + lane];
        const float v1 = x[(size_t)p1.x * D_FEAT + lane];
        const float v2 = x[(size_t)p2.x * D_FEAT + lane];
        const float v3 = x[(size_t)p3.x * D_FEAT + lane];
        a0 = fmaf(v0, __int_as_float(p0.y), a0);
        a1 = fmaf(v1, __int_as_float(p1.y), a1);
        a2 = fmaf(v2, __int_as_float(p2.y), a2);
        a3 = fmaf(v3, __int_as_float(p3.y), a3);
    }
    for (; e < m; ++e) {
        const int2 p = pl[e];
        a0 = fmaf(x[(size_t)p.x * D_FEAT + lane], __int_as_float(p.y), a0);
    }
    float r = (a0 + a1) + (a2 + a3);
    if (*ovf_flag) r += out[(size_t)node * D_FEAT + lane];  // overflow contributions
    out[(size_t)node * D_FEAT + lane] = r;
}

// ---------------- CSR fallback (round-2) ----------------
__global__ __launch_bounds__(256) void mp_hist(
    const int* __restrict__ dst, int* __restrict__ deg, int n_edges)
{
    const int i = blockIdx.x * blockDim.x + threadIdx.x;
    if (i < n_edges) atomicAdd(&deg[dst[i]], 1);
}

__device__ __forceinline__ int wave_incl_scan(int v, int lane) {
    #pragma unroll
    for (int d = 1; d < 64; d <<= 1) {
        int t = __shfl_up(v, d);
        if (lane >= d) v += t;
    }
    return v;
}

__global__ __launch_bounds__(256) void mp_scan_blocksums(
    const int* __restrict__ deg, int* __restrict__ bsums, int n)
{
    __shared__ int wsum[4];
    const int i = blockIdx.x * 256 + threadIdx.x;
    const int lane = threadIdx.x & 63;
    const int wid = threadIdx.x >> 6;
    int v = (i < n) ? deg[i] : 0;
    #pragma unroll
    for (int d = 32; d >= 1; d >>= 1) v += __shfl_down(v, d);
    if (lane == 0) wsum[wid] = v;
    __syncthreads();
    if (threadIdx.x == 0)
        bsums[blockIdx.x] = wsum[0] + wsum[1] + wsum[2] + wsum[3];
}

__global__ __launch_bounds__(1024) void mp_scan_bsums(int* __restrict__ bsums, int nb)
{
    __shared__ int sh[1024];
    const int t = threadIdx.x;
    int v = (t < nb) ? bsums[t] : 0;
    sh[t] = v;
    __syncthreads();
    #pragma unroll
    for (int d = 1; d < 1024; d <<= 1) {
        int addv = (t >= d) ? sh[t - d] : 0;
        __syncthreads();
        sh[t] += addv;
        __syncthreads();
    }
    if (t < nb) bsums[t] = sh[t] - v;
}

__global__ __launch_bounds__(256) void mp_scan_final(
    int* __restrict__ deg_off, int* __restrict__ cursor,
    const int* __restrict__ bsums, int n)
{
    __shared__ int wsum[4];
    const int i = blockIdx.x * 256 + threadIdx.x;
    const int lane = threadIdx.x & 63;
    const int wid = threadIdx.x >> 6;
    int v = (i < n) ? deg_off[i] : 0;
    int incl = wave_incl_scan(v, lane);
    if (lane == 63) wsum[wid] = incl;
    __syncthreads();
    int woff = 0;
    #pragma unroll
    for (int k = 0; k < 4; ++k) woff += (k < wid) ? wsum[k] : 0;
    const int excl = incl - v + woff + bsums[blockIdx.x];
    if (i < n) { deg_off[i] = excl; cursor[i] = excl; }
}

__global__ __launch_bounds__(256) void mp_bucket(
    const int* __restrict__ src, const int* __restrict__ dst,
    const float* __restrict__ w, int* __restrict__ cursor,
    int2* __restrict__ payload, int n_edges)
{
    const int i = blockIdx.x * blockDim.x + threadIdx.x;
    if (i >= n_edges) return;
    const int d = dst[i];
    const int pos = atomicAdd(&cursor[d], 1);
    payload[pos] = make_int2(src[i], __float_as_int(w[i]));
}

__global__ __launch_bounds__(256) void mp_gather(
    const float* __restrict__ x, const int* __restrict__ off,
    const int2* __restrict__ payload, float* __restrict__ out,
    int n_nodes, int n_edges)
{
    const int gtid = blockIdx.x * blockDim.x + threadIdx.x;
    const int node = gtid >> 6;
    const int lane = threadIdx.x & 63;
    if (node >= n_nodes) return;
    const int beg = off[node];
    const int end = (node + 1 < n_nodes) ? off[node + 1] : n_edges;
    float acc = 0.f;
    int e = beg;
    for (; e + 1 < end; e += 2) {
        const int2 p0 = payload[e];
        const int2 p1 = payload[e + 1];
        acc = fmaf(x[(size_t)p0.x * D_FEAT + lane], __int_as_float(p0.y), acc);
        acc = fmaf(x[(size_t)p1.x * D_FEAT + lane], __int_as_float(p1.y), acc);
    }
    if (e < end) {
        const int2 p = payload[e];
        acc = fmaf(x[(size_t)p.x * D_FEAT + lane], __int_as_float(p.y), acc);
    }
    out[(size_t)node * D_FEAT + lane] = acc;
}

extern "C" void kernel_launch(void* const* d_in, const int* in_sizes, int n_in,
                              void* d_out, int out_size, void* d_ws, size_t ws_size,
                              hipStream_t stream)
{
    const float* x          = (const float*)d_in[0];
    const int*   edge_index = (const int*)d_in[1];   // [2, E]
    const float* w          = (const float*)d_in[2]; // [E, 1]
    float*       out        = (float*)d_out;

    const int n_edges = in_sizes[1] / 2;
    const int n_nodes = in_sizes[0] / D_FEAT;
    const int* src = edge_index;
    const int* dst = edge_index + n_edges;

    // ---- preferred: capacity-bucket path ----
    constexpr int C = 32;
    // ws layout: [cnt: n_nodes ints][flag: 1 int][pad to 256B][payload: n_nodes*C int2]
    const size_t head_ints = (((size_t)n_nodes + 1) + 63) & ~(size_t)63;
    const size_t need_cap = head_ints * 4 + (size_t)n_nodes * C * 8;

    if (ws_size >= need_cap) {
        int*  cnt      = (int*)d_ws;
        int*  ovf_flag = cnt + n_nodes;
        int2* payload  = (int2*)((int*)d_ws + head_ints);

        hipMemsetAsync(cnt, 0, head_ints * 4, stream);                    // cnt + flag
        hipMemsetAsync(d_out, 0, (size_t)out_size * sizeof(float), stream); // for overflow atomics
        const int bgrid = (n_edges + 4 * 256 - 1) / (4 * 256);
        mp_bucket_cap<C><<<bgrid, 256, 0, stream>>>(src, dst, w, x, cnt, payload,
                                                    ovf_flag, out, n_edges);
        const int ggrid = ((size_t)n_nodes * 64 + 255) / 256;
        mp_gather_cap<C><<<ggrid, 256, 0, stream>>>(x, cnt, payload, ovf_flag, out, n_nodes);
        return;
    }

    // ---- CSR fallback (round-2) ----
    const int nb = (n_nodes + 255) / 256;
    const size_t nn_pad = ((size_t)n_nodes + 1023) & ~(size_t)1023;
    const size_t need_csr = (2 * nn_pad + 2048 + 2 * (size_t)n_edges) * 4;

    if (ws_size >= need_csr && nb <= 1024) {
        int*  deg_off = (int*)d_ws;
        int*  cursor  = deg_off + nn_pad;
        int*  bsums   = cursor + nn_pad;
        int2* payload = (int2*)(bsums + 2048);

        hipMemsetAsync(deg_off, 0, (size_t)n_nodes * 4, stream);
        mp_hist<<<(n_edges + 255) / 256, 256, 0, stream>>>(dst, deg_off, n_edges);
        mp_scan_blocksums<<<nb, 256, 0, stream>>>(deg_off, bsums, n_nodes);
        mp_scan_bsums<<<1, 1024, 0, stream>>>(bsums, nb);
        mp_scan_final<<<nb, 256, 0, stream>>>(deg_off, cursor, bsums, n_nodes);
        mp_bucket<<<(n_edges + 255) / 256, 256, 0, stream>>>(src, dst, w, cursor, payload, n_edges);
        const int gather_grid = ((size_t)n_nodes * 64 + 255) / 256;
        mp_gather<<<gather_grid, 256, 0, stream>>>(x, deg_off, payload, out, n_nodes, n_edges);
        return;
    }

    // ---- last resort: atomic scatter ----
    hipMemsetAsync(d_out, 0, (size_t)out_size * sizeof(float), stream);
    const int grid = ((size_t)n_edges * 64 + 255) / 256;
    mp_scatter_atomic<<<grid, 256, 0, stream>>>(x, src, dst, w, out, n_edges);
}

// Round 4
// 143.058 us; speedup vs baseline: 2.3792x; 1.3382x over previous
//
#include <hip/hip_runtime.h>
#include <hip/hip_bf16.h>

// MessagePassing: out[dst[e], :] += x[src[e], :] * w[e]
// x: [N, 64] f32, edge_index: [2, E] int32 (row0=src, row1=dst), w: [E,1] f32
// out: [N, 64] f32
//
// Round-4: two-level dst binning to beat the ~18 G-lines/s random-store ceiling.
//  K1 mp_partition: LDS counting-sort by coarse bin (dst>>7), coalesced flush.
//  K2 mp_bin_gather: per-bin LDS counting-sort by node, register accumulate,
//     single coalesced row store per node. No fine-grained global scatter,
//     no out memset.

constexpr int D_FEAT        = 64;
constexpr int BIN_SHIFT     = 7;                  // 128 nodes / bin
constexpr int NODES_PER_BIN = 1 << BIN_SHIFT;
constexpr int NBINS_MAX     = 1024;               // supports n_nodes <= 131072
constexpr int BIN_CAP       = 2048;               // mean 1536 at E/N=12 -> +13 sigma
constexpr int EPB           = 4096;               // edges per partition block
constexpr int OVF_CAP       = 32768;

__device__ __forceinline__ int wave_incl_scan(int v, int lane) {
    #pragma unroll
    for (int d = 1; d < 64; d <<= 1) {
        int t = __shfl_up(v, d);
        if (lane >= d) v += t;
    }
    return v;
}

// ---------------- K1: partition edges into coarse bins ----------------
__global__ __launch_bounds__(512) void mp_partition(
    const int* __restrict__ src, const int* __restrict__ dst,
    const float* __restrict__ w,
    int*  __restrict__ gcnt,       // [nbins] global per-bin cursors (pre-zeroed)
    int2* __restrict__ payload,    // [nbins * BIN_CAP]
    int*  __restrict__ ovf_cnt, int4* __restrict__ ovf,
    int n_edges, int nbins)
{
    __shared__ int cnt[NBINS_MAX];
    __shared__ int start[NBINS_MAX];
    __shared__ int cur[NBINS_MAX];
    __shared__ int gbase[NBINS_MAX];
    __shared__ unsigned short binof[EPB];
    __shared__ int2 sorted[EPB];
    __shared__ int wsum[8];

    const int t    = threadIdx.x;
    const int lane = t & 63;
    const int wid  = t >> 6;
    const int base = blockIdx.x * EPB;
    const int nblk = min(EPB, n_edges - base);

    for (int b = t; b < nbins; b += 512) cnt[b] = 0;
    __syncthreads();

    // count pass (dst only), int4 loads
    #pragma unroll
    for (int k = 0; k < EPB / (4 * 512); ++k) {
        const int i4 = (base >> 2) + k * 512 + t;
        if (i4 * 4 < n_edges) {
            const int4 d4 = reinterpret_cast<const int4*>(dst)[i4];
            atomicAdd(&cnt[d4.x >> BIN_SHIFT], 1);
            atomicAdd(&cnt[d4.y >> BIN_SHIFT], 1);
            atomicAdd(&cnt[d4.z >> BIN_SHIFT], 1);
            atomicAdd(&cnt[d4.w >> BIN_SHIFT], 1);
        }
    }
    __syncthreads();

    // block exclusive scan over nbins (2 bins / thread)
    const int b2 = t * 2;
    const int c0 = (b2     < nbins) ? cnt[b2]     : 0;
    const int c1 = (b2 + 1 < nbins) ? cnt[b2 + 1] : 0;
    const int l  = c0 + c1;
    const int incl = wave_incl_scan(l, lane);
    if (lane == 63) wsum[wid] = incl;
    __syncthreads();
    int woff = 0;
    #pragma unroll
    for (int k = 0; k < 8; ++k) woff += (k < wid) ? wsum[k] : 0;
    const int excl = woff + incl - l;
    if (b2     < nbins) { start[b2]     = excl;      cur[b2]     = excl;      }
    if (b2 + 1 < nbins) { start[b2 + 1] = excl + c0; cur[b2 + 1] = excl + c0; }
    __syncthreads();

    // reserve contiguous global runs (one atomic per non-empty bin per block)
    for (int b = t; b < nbins; b += 512) {
        const int c = cnt[b];
        if (c > 0) gbase[b] = atomicAdd(&gcnt[b], c);
    }

    // scatter into LDS sorted-by-bin order
    #pragma unroll
    for (int k = 0; k < EPB / (4 * 512); ++k) {
        const int i4 = (base >> 2) + k * 512 + t;
        if (i4 * 4 < n_edges) {
            const int4   d4 = reinterpret_cast<const int4*>(dst)[i4];
            const int4   s4 = reinterpret_cast<const int4*>(src)[i4];
            const float4 w4 = reinterpret_cast<const float4*>(w)[i4];
            const int   dd[4] = {d4.x, d4.y, d4.z, d4.w};
            const int   ss[4] = {s4.x, s4.y, s4.z, s4.w};
            const float ww[4] = {w4.x, w4.y, w4.z, w4.w};
            #pragma unroll
            for (int j = 0; j < 4; ++j) {
                const int b   = dd[j] >> BIN_SHIFT;
                const int low = dd[j] & (NODES_PER_BIN - 1);
                const int p   = atomicAdd(&cur[b], 1);
                sorted[p] = make_int2((low << 20) | ss[j], __float_as_int(ww[j]));
                binof[p]  = (unsigned short)b;
            }
        }
    }
    __syncthreads();

    // coalesced flush: consecutive LDS slots -> consecutive global slots per run
    for (int i = t; i < nblk; i += 512) {
        const int b    = binof[i];
        const int idx  = i - start[b];
        const int gpos = gbase[b] + idx;
        const int2 e   = sorted[i];
        if (gpos < BIN_CAP) {
            payload[(size_t)b * BIN_CAP + gpos] = e;
        } else {
            const int op = atomicAdd(ovf_cnt, 1);
            if (op < OVF_CAP)
                ovf[op] = make_int4((b << BIN_SHIFT) + (e.x >> 20),
                                    e.x & 0xFFFFF, e.y, 0);
        }
    }
}

// ---------------- K2: per-bin fine sort (LDS) + gather + row store ----------------
__global__ __launch_bounds__(512) void mp_bin_gather(
    const float* __restrict__ x,
    const int*  __restrict__ gcnt,
    const int2* __restrict__ payload,
    const int*  __restrict__ ovf_cnt, const int4* __restrict__ ovf,
    float* __restrict__ out, int n_nodes)
{
    __shared__ int2 sedge[BIN_CAP];                 // 16 KB
    __shared__ int ncnt[NODES_PER_BIN];
    __shared__ int nstart[NODES_PER_BIN + 1];
    __shared__ int ncur[NODES_PER_BIN];

    const int b    = blockIdx.x;
    const int t    = threadIdx.x;
    const int lane = t & 63;
    const int wid  = t >> 6;

    const int m = min(gcnt[b], BIN_CAP);
    const int2* pl = payload + (size_t)b * BIN_CAP;

    for (int i = t; i < NODES_PER_BIN; i += 512) ncnt[i] = 0;
    __syncthreads();
    for (int i = t; i < m; i += 512)
        atomicAdd(&ncnt[pl[i].x >> 20], 1);
    __syncthreads();

    // exclusive prefix over 128 node counters (wave 0)
    if (t < 64) {
        const int a0 = ncnt[t], a1 = ncnt[64 + t];
        const int s0 = wave_incl_scan(a0, t);
        const int s1 = wave_incl_scan(a1, t);
        const int tot0 = __shfl(s0, 63);
        nstart[t]      = s0 - a0;
        nstart[64 + t] = tot0 + s1 - a1;
        if (t == 63) nstart[128] = tot0 + s1;
    }
    __syncthreads();
    for (int i = t; i < NODES_PER_BIN; i += 512) ncur[i] = nstart[i];
    __syncthreads();

    // scatter into node-sorted LDS order (payload re-read is L2-hot)
    for (int i = t; i < m; i += 512) {
        const int2 e  = pl[i];
        const int p   = atomicAdd(&ncur[e.x >> 20], 1);
        sedge[p] = e;
    }
    __syncthreads();

    const int novf = *ovf_cnt;  // usually 0

    // gather: wave per node (strided), lane = feature
    for (int n = wid; n < NODES_PER_BIN; n += 8) {
        const int node = (b << BIN_SHIFT) + n;
        if (node >= n_nodes) break;
        const int s0 = nstart[n], s1 = nstart[n + 1];
        float a0 = 0.f, a1 = 0.f, a2 = 0.f, a3 = 0.f;
        int e = s0;
        for (; e + 4 <= s1; e += 4) {
            const int2 p0 = sedge[e],     p1 = sedge[e + 1];
            const int2 p2 = sedge[e + 2], p3 = sedge[e + 3];
            a0 = fmaf(x[(size_t)(p0.x & 0xFFFFF) * D_FEAT + lane], __int_as_float(p0.y), a0);
            a1 = fmaf(x[(size_t)(p1.x & 0xFFFFF) * D_FEAT + lane], __int_as_float(p1.y), a1);
            a2 = fmaf(x[(size_t)(p2.x & 0xFFFFF) * D_FEAT + lane], __int_as_float(p2.y), a2);
            a3 = fmaf(x[(size_t)(p3.x & 0xFFFFF) * D_FEAT + lane], __int_as_float(p3.y), a3);
        }
        for (; e < s1; ++e) {
            const int2 p = sedge[e];
            a0 = fmaf(x[(size_t)(p.x & 0xFFFFF) * D_FEAT + lane], __int_as_float(p.y), a0);
        }
        float r = (a0 + a1) + (a2 + a3);
        if (novf > 0) {  // rare overflow path
            const int lim = min(novf, OVF_CAP);
            for (int j = 0; j < lim; ++j) {
                const int4 o = ovf[j];
                if (o.x == node)
                    r = fmaf(x[(size_t)o.y * D_FEAT + lane], __int_as_float(o.z), r);
            }
        }
        out[(size_t)node * D_FEAT + lane] = r;
    }
}

// ---------------- fallback: atomic scatter (round-1, known correct) ----------------
__global__ __launch_bounds__(256) void mp_scatter_atomic(
    const float* __restrict__ x, const int* __restrict__ src,
    const int* __restrict__ dst, const float* __restrict__ w,
    float* __restrict__ out, int n_edges)
{
    const int gtid = blockIdx.x * blockDim.x + threadIdx.x;
    const int edge = gtid >> 6;
    const int lane = threadIdx.x & 63;
    if (edge >= n_edges) return;
    const int s = src[edge];
    const int d = dst[edge];
    const float ww = w[edge];
    atomicAdd(&out[(size_t)d * D_FEAT + lane], x[(size_t)s * D_FEAT + lane] * ww);
}

extern "C" void kernel_launch(void* const* d_in, const int* in_sizes, int n_in,
                              void* d_out, int out_size, void* d_ws, size_t ws_size,
                              hipStream_t stream)
{
    const float* x          = (const float*)d_in[0];
    const int*   edge_index = (const int*)d_in[1];   // [2, E]
    const float* w          = (const float*)d_in[2]; // [E, 1]
    float*       out        = (float*)d_out;

    const int n_edges = in_sizes[1] / 2;
    const int n_nodes = in_sizes[0] / D_FEAT;
    const int* src = edge_index;
    const int* dst = edge_index + n_edges;

    const int nbins = (n_nodes + NODES_PER_BIN - 1) >> BIN_SHIFT;

    // ws layout: gcnt[NBINS_MAX] | ovf_cnt(+pad to 64 ints) | ovf[OVF_CAP] int4 | payload[nbins*BIN_CAP] int2
    int*  gcnt    = (int*)d_ws;
    int*  ovf_cnt = gcnt + NBINS_MAX;
    int4* ovf     = (int4*)(gcnt + NBINS_MAX + 64);
    int2* payload = (int2*)(ovf + OVF_CAP);
    const size_t need = (size_t)(NBINS_MAX + 64) * 4 + (size_t)OVF_CAP * 16
                      + (size_t)nbins * BIN_CAP * 8;

    const bool ok = (ws_size >= need) && (nbins <= NBINS_MAX) && ((n_edges & 3) == 0);

    if (ok) {
        // zero bin cursors + overflow counter (payload needs no init)
        hipMemsetAsync(gcnt, 0, (size_t)(NBINS_MAX + 64) * 4, stream);
        const int g1 = (n_edges + EPB - 1) / EPB;
        mp_partition<<<g1, 512, 0, stream>>>(src, dst, w, gcnt, payload,
                                             ovf_cnt, ovf, n_edges, nbins);
        mp_bin_gather<<<nbins, 512, 0, stream>>>(x, gcnt, payload,
                                                 ovf_cnt, ovf, out, n_nodes);
        return;
    }

    // fallback: atomic scatter
    hipMemsetAsync(d_out, 0, (size_t)out_size * sizeof(float), stream);
    const int grid = (int)(((size_t)n_edges * 64 + 255) / 256);
    mp_scatter_atomic<<<grid, 256, 0, stream>>>(x, src, dst, w, out, n_edges);
}

// Round 5
// 136.842 us; speedup vs baseline: 2.4873x; 1.0454x over previous
//
#include <hip/hip_runtime.h>
#include <hip/hip_bf16.h>

// MessagePassing: out[dst[e], :] += x[src[e], :] * w[e]
// x: [N, 64] f32, edge_index: [2, E] int32 (row0=src, row1=dst), w: [E,1] f32
// out: [N, 64] f32
//
// Round-5: r4 structure (coarse-bin partition -> per-bin LDS sort + gather)
// with (a) partition at 1024 thr (full occupancy at 56 KB LDS) and
// (b) gather with 8 independent gather streams + single payload global read.

constexpr int D_FEAT        = 64;
constexpr int BIN_SHIFT     = 7;                  // 128 nodes / bin
constexpr int NODES_PER_BIN = 1 << BIN_SHIFT;
constexpr int NBINS_MAX     = 1024;               // supports n_nodes <= 131072
constexpr int BIN_CAP       = 2048;               // mean 1536 at E/N=12 -> +13 sigma
constexpr int EPB           = 4096;               // edges per partition block
constexpr int OVF_CAP       = 32768;

__device__ __forceinline__ int wave_incl_scan(int v, int lane) {
    #pragma unroll
    for (int d = 1; d < 64; d <<= 1) {
        int t = __shfl_up(v, d);
        if (lane >= d) v += t;
    }
    return v;
}

// ---------------- K1: partition edges into coarse bins (1024 thr) ----------------
__global__ __launch_bounds__(1024) void mp_partition(
    const int* __restrict__ src, const int* __restrict__ dst,
    const float* __restrict__ w,
    int*  __restrict__ gcnt,       // [nbins] global per-bin cursors (pre-zeroed)
    int2* __restrict__ payload,    // [nbins * BIN_CAP]
    int*  __restrict__ ovf_cnt, int4* __restrict__ ovf,
    int n_edges, int nbins)
{
    __shared__ int cnt[NBINS_MAX];
    __shared__ int start[NBINS_MAX];
    __shared__ int cur[NBINS_MAX];
    __shared__ int gbase[NBINS_MAX];
    __shared__ unsigned short binof[EPB];
    __shared__ int2 sorted[EPB];
    __shared__ int wsum[16];

    const int t    = threadIdx.x;
    const int lane = t & 63;
    const int wid  = t >> 6;
    const int base = blockIdx.x * EPB;
    const int nblk = min(EPB, n_edges - base);

    if (t < NBINS_MAX) cnt[t] = 0;
    __syncthreads();

    // count pass (dst only), one int4 per thread
    const int i4 = (base >> 2) + t;
    int4 d4 = make_int4(0, 0, 0, 0);
    bool have = (i4 * 4 < n_edges);
    if (have) {
        d4 = reinterpret_cast<const int4*>(dst)[i4];
        atomicAdd(&cnt[d4.x >> BIN_SHIFT], 1);
        atomicAdd(&cnt[d4.y >> BIN_SHIFT], 1);
        atomicAdd(&cnt[d4.z >> BIN_SHIFT], 1);
        atomicAdd(&cnt[d4.w >> BIN_SHIFT], 1);
    }
    __syncthreads();

    // block exclusive scan over nbins (1 bin / thread, nbins <= 1024)
    const int c = (t < nbins) ? cnt[t] : 0;
    const int incl = wave_incl_scan(c, lane);
    if (lane == 63) wsum[wid] = incl;
    __syncthreads();
    int woff = 0;
    #pragma unroll
    for (int k = 0; k < 16; ++k) woff += (k < wid) ? wsum[k] : 0;
    const int excl = woff + incl - c;
    if (t < nbins) {
        start[t] = excl;
        cur[t]   = excl;
        // reserve contiguous global run (one atomic per non-empty bin per block)
        if (c > 0) gbase[t] = atomicAdd(&gcnt[t], c);
    }
    __syncthreads();

    // scatter into LDS sorted-by-bin order
    if (have) {
        const int4   s4 = reinterpret_cast<const int4*>(src)[i4];
        const float4 w4 = reinterpret_cast<const float4*>(w)[i4];
        const int   dd[4] = {d4.x, d4.y, d4.z, d4.w};
        const int   ss[4] = {s4.x, s4.y, s4.z, s4.w};
        const float ww[4] = {w4.x, w4.y, w4.z, w4.w};
        #pragma unroll
        for (int j = 0; j < 4; ++j) {
            const int b   = dd[j] >> BIN_SHIFT;
            const int low = dd[j] & (NODES_PER_BIN - 1);
            const int p   = atomicAdd(&cur[b], 1);
            sorted[p] = make_int2((low << 20) | ss[j], __float_as_int(ww[j]));
            binof[p]  = (unsigned short)b;
        }
    }
    __syncthreads();

    // coalesced flush: consecutive LDS slots -> consecutive global slots per run
    #pragma unroll
    for (int k = 0; k < EPB / 1024; ++k) {
        const int i = k * 1024 + t;
        if (i >= nblk) break;
        const int b    = binof[i];
        const int idx  = i - start[b];
        const int gpos = gbase[b] + idx;
        const int2 e   = sorted[i];
        if (gpos < BIN_CAP) {
            payload[(size_t)b * BIN_CAP + gpos] = e;
        } else {
            const int op = atomicAdd(ovf_cnt, 1);
            if (op < OVF_CAP)
                ovf[op] = make_int4((b << BIN_SHIFT) + (e.x >> 20),
                                    e.x & 0xFFFFF, e.y, 0);
        }
    }
}

// ---------------- K2: per-bin fine sort (LDS) + gather + row store ----------------
__global__ __launch_bounds__(512) void mp_bin_gather(
    const float* __restrict__ x,
    const int*  __restrict__ gcnt,
    const int2* __restrict__ payload,
    const int*  __restrict__ ovf_cnt, const int4* __restrict__ ovf,
    float* __restrict__ out, int n_nodes)
{
    __shared__ int2 sraw[BIN_CAP];                  // 16 KB (global staged once)
    __shared__ int2 sedge[BIN_CAP];                 // 16 KB (node-sorted)
    __shared__ int ncnt[NODES_PER_BIN];
    __shared__ int nstart[NODES_PER_BIN + 1];
    __shared__ int ncur[NODES_PER_BIN];

    const int b    = blockIdx.x;
    const int t    = threadIdx.x;
    const int lane = t & 63;
    const int wid  = t >> 6;

    const int m = min(gcnt[b], BIN_CAP);
    const int2* pl = payload + (size_t)b * BIN_CAP;

    for (int i = t; i < NODES_PER_BIN; i += 512) ncnt[i] = 0;
    __syncthreads();

    // stage payload into LDS once + histogram by node
    for (int i = t; i < m; i += 512) {
        const int2 e = pl[i];
        sraw[i] = e;
        atomicAdd(&ncnt[e.x >> 20], 1);
    }
    __syncthreads();

    // exclusive prefix over 128 node counters (wave 0)
    if (t < 64) {
        const int a0 = ncnt[t], a1 = ncnt[64 + t];
        const int s0 = wave_incl_scan(a0, t);
        const int s1 = wave_incl_scan(a1, t);
        const int tot0 = __shfl(s0, 63);
        nstart[t]      = s0 - a0;
        nstart[64 + t] = tot0 + s1 - a1;
        if (t == 63) nstart[128] = tot0 + s1;
    }
    __syncthreads();
    for (int i = t; i < NODES_PER_BIN; i += 512) ncur[i] = nstart[i];
    __syncthreads();

    // LDS -> LDS node-sorted scatter
    for (int i = t; i < m; i += 512) {
        const int2 e = sraw[i];
        const int p  = atomicAdd(&ncur[e.x >> 20], 1);
        sedge[p] = e;
    }
    __syncthreads();

    const int novf = *ovf_cnt;  // usually 0

    // gather: wave per node (strided), lane = feature, 8 independent streams
    for (int n = wid; n < NODES_PER_BIN; n += 8) {
        const int node = (b << BIN_SHIFT) + n;
        if (node >= n_nodes) break;
        const int s0 = nstart[n], s1 = nstart[n + 1];
        float a0 = 0.f, a1 = 0.f, a2 = 0.f, a3 = 0.f;
        float a4 = 0.f, a5 = 0.f, a6 = 0.f, a7 = 0.f;
        int e = s0;
        for (; e + 8 <= s1; e += 8) {
            const int2 p0 = sedge[e],     p1 = sedge[e + 1];
            const int2 p2 = sedge[e + 2], p3 = sedge[e + 3];
            const int2 p4 = sedge[e + 4], p5 = sedge[e + 5];
            const int2 p6 = sedge[e + 6], p7 = sedge[e + 7];
            a0 = fmaf(x[(size_t)(p0.x & 0xFFFFF) * D_FEAT + lane], __int_as_float(p0.y), a0);
            a1 = fmaf(x[(size_t)(p1.x & 0xFFFFF) * D_FEAT + lane], __int_as_float(p1.y), a1);
            a2 = fmaf(x[(size_t)(p2.x & 0xFFFFF) * D_FEAT + lane], __int_as_float(p2.y), a2);
            a3 = fmaf(x[(size_t)(p3.x & 0xFFFFF) * D_FEAT + lane], __int_as_float(p3.y), a3);
            a4 = fmaf(x[(size_t)(p4.x & 0xFFFFF) * D_FEAT + lane], __int_as_float(p4.y), a4);
            a5 = fmaf(x[(size_t)(p5.x & 0xFFFFF) * D_FEAT + lane], __int_as_float(p5.y), a5);
            a6 = fmaf(x[(size_t)(p6.x & 0xFFFFF) * D_FEAT + lane], __int_as_float(p6.y), a6);
            a7 = fmaf(x[(size_t)(p7.x & 0xFFFFF) * D_FEAT + lane], __int_as_float(p7.y), a7);
        }
        if (e + 4 <= s1) {
            const int2 p0 = sedge[e],     p1 = sedge[e + 1];
            const int2 p2 = sedge[e + 2], p3 = sedge[e + 3];
            a0 = fmaf(x[(size_t)(p0.x & 0xFFFFF) * D_FEAT + lane], __int_as_float(p0.y), a0);
            a1 = fmaf(x[(size_t)(p1.x & 0xFFFFF) * D_FEAT + lane], __int_as_float(p1.y), a1);
            a2 = fmaf(x[(size_t)(p2.x & 0xFFFFF) * D_FEAT + lane], __int_as_float(p2.y), a2);
            a3 = fmaf(x[(size_t)(p3.x & 0xFFFFF) * D_FEAT + lane], __int_as_float(p3.y), a3);
            e += 4;
        }
        for (; e < s1; ++e) {
            const int2 p = sedge[e];
            a0 = fmaf(x[(size_t)(p.x & 0xFFFFF) * D_FEAT + lane], __int_as_float(p.y), a0);
        }
        float r = ((a0 + a1) + (a2 + a3)) + ((a4 + a5) + (a6 + a7));
        if (novf > 0) {  // rare overflow path
            const int lim = min(novf, OVF_CAP);
            for (int j = 0; j < lim; ++j) {
                const int4 o = ovf[j];
                if (o.x == node)
                    r = fmaf(x[(size_t)o.y * D_FEAT + lane], __int_as_float(o.z), r);
            }
        }
        out[(size_t)node * D_FEAT + lane] = r;
    }
}

// ---------------- fallback: atomic scatter (round-1, known correct) ----------------
__global__ __launch_bounds__(256) void mp_scatter_atomic(
    const float* __restrict__ x, const int* __restrict__ src,
    const int* __restrict__ dst, const float* __restrict__ w,
    float* __restrict__ out, int n_edges)
{
    const int gtid = blockIdx.x * blockDim.x + threadIdx.x;
    const int edge = gtid >> 6;
    const int lane = threadIdx.x & 63;
    if (edge >= n_edges) return;
    const int s = src[edge];
    const int d = dst[edge];
    const float ww = w[edge];
    atomicAdd(&out[(size_t)d * D_FEAT + lane], x[(size_t)s * D_FEAT + lane] * ww);
}

extern "C" void kernel_launch(void* const* d_in, const int* in_sizes, int n_in,
                              void* d_out, int out_size, void* d_ws, size_t ws_size,
                              hipStream_t stream)
{
    const float* x          = (const float*)d_in[0];
    const int*   edge_index = (const int*)d_in[1];   // [2, E]
    const float* w          = (const float*)d_in[2]; // [E, 1]
    float*       out        = (float*)d_out;

    const int n_edges = in_sizes[1] / 2;
    const int n_nodes = in_sizes[0] / D_FEAT;
    const int* src = edge_index;
    const int* dst = edge_index + n_edges;

    const int nbins = (n_nodes + NODES_PER_BIN - 1) >> BIN_SHIFT;

    // ws layout: gcnt[NBINS_MAX] | ovf_cnt(+pad to 64 ints) | ovf[OVF_CAP] int4 | payload[nbins*BIN_CAP] int2
    int*  gcnt    = (int*)d_ws;
    int*  ovf_cnt = gcnt + NBINS_MAX;
    int4* ovf     = (int4*)(gcnt + NBINS_MAX + 64);
    int2* payload = (int2*)(ovf + OVF_CAP);
    const size_t need = (size_t)(NBINS_MAX + 64) * 4 + (size_t)OVF_CAP * 16
                      + (size_t)nbins * BIN_CAP * 8;

    const bool ok = (ws_size >= need) && (nbins <= NBINS_MAX) && ((n_edges & 3) == 0);

    if (ok) {
        // zero bin cursors + overflow counter (payload needs no init)
        hipMemsetAsync(gcnt, 0, (size_t)(NBINS_MAX + 64) * 4, stream);
        const int g1 = (n_edges + EPB - 1) / EPB;
        mp_partition<<<g1, 1024, 0, stream>>>(src, dst, w, gcnt, payload,
                                              ovf_cnt, ovf, n_edges, nbins);
        mp_bin_gather<<<nbins, 512, 0, stream>>>(x, gcnt, payload,
                                                 ovf_cnt, ovf, out, n_nodes);
        return;
    }

    // fallback: atomic scatter
    hipMemsetAsync(d_out, 0, (size_t)out_size * sizeof(float), stream);
    const int grid = (int)(((size_t)n_edges * 64 + 255) / 256);
    mp_scatter_atomic<<<grid, 256, 0, stream>>>(x, src, dst, w, out, n_edges);
}